// Round 1
// baseline (554.209 us; speedup 1.0000x reference)
//
#include <hip/hip_runtime.h>
#include <hip/hip_cooperative_groups.h>
#include <math.h>

namespace cg = cooperative_groups;

#define N_NODES   15000
#define N_EDGES   60000
#define EVOCAB    54
#define NODE_INDIM 64
#define EDGE_INDIM 32
#define H  32
#define EH 64
#define N_BOND 4

// ---- fused-kernel phase-0 task layout (all segment starts 32/64-aligned) ----
#define TASK_VOCAB (EVOCAB * 1024)                 // 55296  (64-aligned)
#define TASK_PROJ  (N_NODES * H)                   // 480000
#define TASK_PACK  (H * H)                         // 1024 (gru weight repack)
#define PH0_TOTAL  (TASK_VOCAB + TASK_PROJ + TASK_PACK + N_NODES)  // +rs zero

// ===========================================================================
// Cooperative mega-kernel: 1 launch for the whole model.
//  P0: vocab 54x32x32 weight table | h0 projection | GRU weight pack | rs=0
//  P1: in-degree count (int atomics, once)
//  P2: exclusive prefix scan of degrees (block 0 only)
//  P3: scatter edges sorted by dst:  edge_p[pos] = src | (vocab<<16)
//  P4-6: 3 message-passing steps, each ONE phase: per-dst gather (attention
//        logit + exp + 32x32 matvec, contiguous CSR reads, NO atomics) fused
//        with softmax-normalize + relu + GRU cell. h double-buffered.
// ===========================================================================
__global__ __launch_bounds__(256)
void fused_kernel(const int* __restrict__ node_ids, const int* __restrict__ edge_ids,
                  const int* __restrict__ src, const int* __restrict__ dst,
                  const float* __restrict__ node_table, const float* __restrict__ edge_table,
                  const float* __restrict__ proj_W, const float* __restrict__ proj_b,
                  const float* __restrict__ attn_w,
                  const float* __restrict__ e1_W1, const float* __restrict__ e1_b1,
                  const float* __restrict__ e1_W2, const float* __restrict__ e1_b2,
                  const float* __restrict__ e2_W1, const float* __restrict__ e2_b1,
                  const float* __restrict__ e2_W2, const float* __restrict__ e2_b2,
                  const float* __restrict__ gWih, const float* __restrict__ gWhh,
                  const float* __restrict__ gbih, const float* __restrict__ gbhh,
                  float* __restrict__ Wt, float* __restrict__ h0, float* __restrict__ h1,
                  int* __restrict__ rs, int* __restrict__ edge_p,
                  float4* __restrict__ Wpk4, float2* __restrict__ Wpk2,
                  float* __restrict__ out)
{
    cg::grid_group grid = cg::this_grid();
    const int T  = gridDim.x * 256;               // multiple of 64 -> wave-aligned strides
    const int t0 = blockIdx.x * 256 + threadIdx.x;

    // ---------------- Phase 0 --------------------------------------------
    for (int t = t0; t < PH0_TOTAL; t += T) {
        if (t < TASK_VOCAB) {
            int v = t >> 10, f = t & 1023, l = t & 63;   // v wave-uniform
            const float* W1 = (v < N_BOND) ? e1_W1 : e2_W1;
            const float* b1 = (v < N_BOND) ? e1_b1 : e2_b1;
            const float* W2 = (v < N_BOND) ? e1_W2 : e2_W2;
            const float* b2 = (v < N_BOND) ? e1_b2 : e2_b2;
            const float* ef = edge_table + v * EDGE_INDIM;
            float z = b1[l];
            const float* w1r = W1 + l * EDGE_INDIM;
            #pragma unroll
            for (int j = 0; j < EDGE_INDIM; ++j) z += ef[j] * w1r[j];
            z = fmaxf(z, 0.f);
            float y = b2[f];
            const float* w2r = W2 + f * EH;
            #pragma unroll
            for (int k = 0; k < EH; ++k) y += __shfl(z, k, 64) * w2r[k];
            Wt[(v << 10) + f] = y;                       // [v][i*32+o]
        } else if (t < TASK_VOCAB + TASK_PROJ) {
            int q = t - TASK_VOCAB;
            int n = q >> 5, o = q & 31;
            int gid = node_ids[n];
            const float* nf = node_table + (size_t)gid * NODE_INDIM;
            const float* wr = proj_W + o * NODE_INDIM;
            float acc = proj_b[o];
            #pragma unroll 8
            for (int j = 0; j < NODE_INDIM; ++j) acc += nf[j] * wr[j];
            h0[q] = fmaxf(acc, 0.f);
        } else if (t < TASK_VOCAB + TASK_PROJ + TASK_PACK) {
            int q = t - (TASK_VOCAB + TASK_PROJ);        // q = j*32 + o
            int j = q >> 5, o = q & 31;
            Wpk4[q] = make_float4(gWih[o * 32 + j], gWih[(32 + o) * 32 + j],
                                  gWih[(64 + o) * 32 + j], gWhh[o * 32 + j]);
            Wpk2[q] = make_float2(gWhh[(32 + o) * 32 + j], gWhh[(64 + o) * 32 + j]);
        } else {
            rs[t - (TASK_VOCAB + TASK_PROJ + TASK_PACK)] = 0;
        }
    }
    grid.sync();

    // ---------------- Phase 1: degree count ------------------------------
    for (int e = t0; e < N_EDGES; e += T) atomicAdd(&rs[dst[e]], 1);
    grid.sync();

    // ---------------- Phase 2: exclusive scan (block 0) ------------------
    if (blockIdx.x == 0) {
        __shared__ int s_sum[256];
        __shared__ int s_wsum[4];
        const int CH = (N_NODES + 255) / 256;            // 59
        int base = threadIdx.x * CH;
        int sum = 0;
        for (int k = 0; k < CH; ++k) { int i = base + k; if (i < N_NODES) sum += rs[i]; }
        s_sum[threadIdx.x] = sum;
        __syncthreads();
        int lane = threadIdx.x & 63, wv = threadIdx.x >> 6;
        int v = s_sum[threadIdx.x];
        #pragma unroll
        for (int off = 1; off < 64; off <<= 1) {
            int u = __shfl_up(v, off, 64);
            if (lane >= off) v += u;
        }
        if (lane == 63) s_wsum[wv] = v;
        __syncthreads();
        int wbase = 0;
        for (int w = 0; w < wv; ++w) wbase += s_wsum[w];
        int run = wbase + (v - sum);                     // exclusive thread prefix
        for (int k = 0; k < CH; ++k) {
            int i = base + k;
            if (i < N_NODES) { int d = rs[i]; rs[i] = run; run += d; }
        }
    }
    grid.sync();

    // ---------------- Phase 3: scatter sorted-by-dst ---------------------
    for (int e = t0; e < N_EDGES; e += T) {
        int pos = atomicAdd(&rs[dst[e]], 1);
        edge_p[pos] = src[e] | (edge_ids[e] << 16);      // src<2^14, vocab<54
    }
    grid.sync();
    // post-scatter: rs[n] = end(n);  start(n) = n ? rs[n-1] : 0

    // ---------------- Phases 4-6: 3 MP steps (gather + GRU fused) --------
    float* hc = h0;
    float* hn = h1;
    for (int step = 0; step < 3; ++step) {
        float* op = (step == 2) ? out : hn;
        for (int t = t0; t < N_NODES * H; t += T) {
            int n = t >> 5, o = t & 31;
            int pbeg = (n == 0) ? 0 : rs[n - 1];
            int pend = rs[n];
            float hv = hc[t];
            float w1 = attn_w[o], w2 = attn_w[32 + o];
            // dst half of the attention logit: per-node constant
            float bd = hv * w2;
            #pragma unroll
            for (int k = 16; k > 0; k >>= 1) bd += __shfl_xor(bd, k, 32);
            float sex = 0.f, acc = 0.f;
            for (int p = pbeg; p < pend; ++p) {
                int pk = edge_p[p];
                int sp = pk & 0xFFFF, vp = pk >> 16;
                float hs = hc[(sp << 5) + o];
                float as = hs * w1;
                #pragma unroll
                for (int k = 16; k > 0; k >>= 1) as += __shfl_xor(as, k, 32);
                float a = as + bd;
                a = (a > 0.f) ? a : 0.01f * a;           // leaky_relu
                float ex = __expf(a);
                sex += ex;
                const float* W = Wt + (vp << 10) + o;    // column o, rows 128B apart
                float y = 0.f;
                #pragma unroll
                for (int i = 0; i < 32; ++i) y += __shfl(hs, i, 32) * W[i * 32];
                acc += ex * y;
            }
            float m = (pend > pbeg) ? fmaxf(acc / sex, 0.f) : 0.f;
            // GRU cell (packed-transposed weights: coalesced broadcast reads)
            float gir = 0.f, giz = 0.f, gin = 0.f, ghr = 0.f, ghz = 0.f, ghn = 0.f;
            #pragma unroll 4
            for (int j = 0; j < 32; ++j) {
                float mj = __shfl(m, j, 32);
                float hj = __shfl(hv, j, 32);
                float4 a4 = Wpk4[j * 32 + o];
                float2 b2 = Wpk2[j * 32 + o];
                gir += mj * a4.x;  giz += mj * a4.y;  gin += mj * a4.z;
                ghr += hj * a4.w;  ghz += hj * b2.x;  ghn += hj * b2.y;
            }
            float r  = 1.f / (1.f + __expf(-(gir + gbih[o]      + ghr + gbhh[o])));
            float z  = 1.f / (1.f + __expf(-(giz + gbih[32 + o] + ghz + gbhh[32 + o])));
            float nn = tanhf(gin + gbih[64 + o] + r * (ghn + gbhh[64 + o]));
            op[t] = (1.f - z) * nn + z * hv;
        }
        if (step < 2) grid.sync();
        float* tmp = hc; hc = hn; hn = tmp;
    }
}

// ===========================================================================
// Fallback path (previous 7-launch version, verbatim except TASK_PACK=1024)
// used only if the cooperative launch is unavailable.
// ===========================================================================
#define FB_TASK_ZERO ((N_NODES * H + N_NODES) / 4)
#define FB_TA (TASK_VOCAB + TASK_PROJ + FB_TASK_ZERO + TASK_PACK)

__global__ void setup_kernel(const int* __restrict__ node_ids,
                             const float* __restrict__ node_table,
                             const float* __restrict__ edge_table,
                             const float* __restrict__ proj_W, const float* __restrict__ proj_b,
                             const float* __restrict__ e1_W1, const float* __restrict__ e1_b1,
                             const float* __restrict__ e1_W2, const float* __restrict__ e1_b2,
                             const float* __restrict__ e2_W1, const float* __restrict__ e2_b1,
                             const float* __restrict__ e2_W2, const float* __restrict__ e2_b2,
                             const float* __restrict__ gWih, const float* __restrict__ gWhh,
                             float* __restrict__ Wt, float* __restrict__ h,
                             float* __restrict__ agg,
                             float4* __restrict__ Wpk4, float2* __restrict__ Wpk2) {
    int t = blockIdx.x * 256 + threadIdx.x;
    if (t >= FB_TA) return;
    if (t < TASK_VOCAB) {
        int v = t >> 10, f = t & 1023, l = t & 63;
        const float* W1 = (v < N_BOND) ? e1_W1 : e2_W1;
        const float* b1 = (v < N_BOND) ? e1_b1 : e2_b1;
        const float* W2 = (v < N_BOND) ? e1_W2 : e2_W2;
        const float* b2 = (v < N_BOND) ? e1_b2 : e2_b2;
        const float* ef = edge_table + v * EDGE_INDIM;
        float z = b1[l];
        const float* w1r = W1 + l * EDGE_INDIM;
        #pragma unroll
        for (int j = 0; j < EDGE_INDIM; ++j) z += ef[j] * w1r[j];
        z = fmaxf(z, 0.f);
        float y = b2[f];
        const float* w2r = W2 + f * EH;
        #pragma unroll
        for (int k = 0; k < EH; ++k) y += __shfl(z, k, 64) * w2r[k];
        Wt[v * 1024 + f] = y;
    } else if (t < TASK_VOCAB + TASK_PROJ) {
        int q = t - TASK_VOCAB;
        int n = q >> 5, o = q & 31;
        int gid = node_ids[n];
        const float* nf = node_table + (size_t)gid * NODE_INDIM;
        const float* wr = proj_W + o * NODE_INDIM;
        float acc = proj_b[o];
        #pragma unroll 8
        for (int j = 0; j < NODE_INDIM; ++j) acc += nf[j] * wr[j];
        h[q] = fmaxf(acc, 0.f);
    } else if (t < TASK_VOCAB + TASK_PROJ + FB_TASK_ZERO) {
        int q = t - TASK_VOCAB - TASK_PROJ;
        ((float4*)agg)[q] = make_float4(0.f, 0.f, 0.f, 0.f);
    } else {
        int q = t - TASK_VOCAB - TASK_PROJ - FB_TASK_ZERO;
        int j = q >> 5, o = q & 31;
        Wpk4[q] = make_float4(gWih[o * 32 + j], gWih[(32 + o) * 32 + j],
                              gWih[(64 + o) * 32 + j], gWhh[o * 32 + j]);
        Wpk2[q] = make_float2(gWhh[(32 + o) * 32 + j], gWhh[(64 + o) * 32 + j]);
    }
}

__launch_bounds__(256)
__global__ void edge_kernel(const int* __restrict__ src, const int* __restrict__ dst,
                            const int* __restrict__ edge_ids,
                            const float* __restrict__ h, const float* __restrict__ Wt,
                            const float* __restrict__ attn_w,
                            float* __restrict__ agg, float* __restrict__ sm) {
    int t = blockIdx.x * 256 + threadIdx.x;
    int e = t >> 5, o = t & 31;
    int s = src[e], d = dst[e], v = edge_ids[e];
    float hs = h[s * 32 + o];
    float val = hs * attn_w[o] + h[d * 32 + o] * attn_w[32 + o];
    #pragma unroll
    for (int k = 16; k > 0; k >>= 1) val += __shfl_xor(val, k, 32);
    float a  = (val > 0.f) ? val : 0.01f * val;
    float ex = __expf(a);
    const float* W = Wt + v * 1024 + o;
    float y = 0.f;
    #pragma unroll
    for (int i = 0; i < 32; ++i)
        y += __shfl(hs, i, 32) * W[i * 32];
    atomicAdd(&agg[d * 32 + o], ex * y);
    if (o == 0) atomicAdd(&sm[d], ex);
}

__launch_bounds__(256)
__global__ void gru_kernel(float* __restrict__ agg, float* __restrict__ sm,
                           const float* __restrict__ h,
                           const float4* __restrict__ Wpk4, const float2* __restrict__ Wpk2,
                           const float* __restrict__ gbih, const float* __restrict__ gbhh,
                           float* __restrict__ hout) {
    int t = blockIdx.x * 256 + threadIdx.x;
    int n = t >> 5, o = t & 31;
    float sinv = 1.f / sm[n];
    float m  = fmaxf(agg[t] * sinv, 0.f);
    float hv = h[t];
    float gir = 0.f, giz = 0.f, gin = 0.f, ghr = 0.f, ghz = 0.f, ghn = 0.f;
    #pragma unroll 8
    for (int j = 0; j < 32; ++j) {
        float mj = __shfl(m, j, 32);
        float hj = __shfl(hv, j, 32);
        float4 a = Wpk4[j * 32 + o];
        float2 b = Wpk2[j * 32 + o];
        gir += mj * a.x;  giz += mj * a.y;  gin += mj * a.z;
        ghr += hj * a.w;  ghz += hj * b.x;  ghn += hj * b.y;
    }
    float r  = 1.f / (1.f + __expf(-(gir + gbih[o]      + ghr + gbhh[o])));
    float z  = 1.f / (1.f + __expf(-(giz + gbih[32 + o] + ghz + gbhh[32 + o])));
    float nn = tanhf(gin + gbih[64 + o] + r * (ghn + gbhh[64 + o]));
    hout[t] = (1.f - z) * nn + z * hv;
    agg[t] = 0.f;
    if (o == 0) sm[n] = 0.f;
}

// ===========================================================================
extern "C" void kernel_launch(void* const* d_in, const int* in_sizes, int n_in,
                              void* d_out, int out_size, void* d_ws, size_t ws_size,
                              hipStream_t stream) {
    const int*   node_ids   = (const int*)d_in[0];
    const int*   edge_ids   = (const int*)d_in[1];
    const int*   srcp       = (const int*)d_in[2];
    const int*   dstp       = (const int*)d_in[3];
    const float* node_table = (const float*)d_in[4];
    const float* edge_table = (const float*)d_in[5];
    const float* proj_W     = (const float*)d_in[6];
    const float* proj_b     = (const float*)d_in[7];
    const float* attn_w     = (const float*)d_in[8];
    const float* e1_W1 = (const float*)d_in[9];  const float* e1_b1 = (const float*)d_in[10];
    const float* e1_W2 = (const float*)d_in[11]; const float* e1_b2 = (const float*)d_in[12];
    const float* e2_W1 = (const float*)d_in[13]; const float* e2_b1 = (const float*)d_in[14];
    const float* e2_W2 = (const float*)d_in[15]; const float* e2_b2 = (const float*)d_in[16];
    const float* gWih  = (const float*)d_in[17]; const float* gWhh  = (const float*)d_in[18];
    const float* gbih  = (const float*)d_in[19]; const float* gbhh  = (const float*)d_in[20];
    float* outp = (float*)d_out;

    char* ws = (char*)d_ws;
    // coop layout: Wt | h0 | h1 | rs | edge_p | Wpk4 | Wpk2   (~4.39 MB)
    float*  Wt   = (float*)(ws);                       // 221184 B
    float*  h0b  = (float*)(ws + 221184);              // 1920000 B
    float*  h1b  = (float*)(ws + 2141184);             // 1920000 B
    int*    rs   = (int*)  (ws + 4061184);             // 60000 B
    int*    ep   = (int*)  (ws + 4121184);             // 240000 B
    float4* Wpk4 = (float4*)(ws + 4361184);            // 16384 B
    float2* Wpk2 = (float2*)(ws + 4377568);            // 8192 B

    // occupancy-sized cooperative grid (cached across calls)
    static int coop_grid = -2;
    if (coop_grid == -2) {
        int nb = 0;
        hipError_t qe = hipOccupancyMaxActiveBlocksPerMultiprocessor(&nb, fused_kernel, 256, 0);
        if (qe == hipSuccess && nb > 0) {
            long g = (long)nb * 256;                   // nb blocks/CU x 256 CUs
            if (g > 2048) g = 2048;
            coop_grid = (int)g;
        } else {
            coop_grid = -1;                            // no coop
        }
        (void)hipGetLastError();
    }

    hipError_t lerr = hipErrorUnknown;
    if (coop_grid > 0) {
        void* args[] = {
            (void*)&node_ids, (void*)&edge_ids, (void*)&srcp, (void*)&dstp,
            (void*)&node_table, (void*)&edge_table, (void*)&proj_W, (void*)&proj_b,
            (void*)&attn_w,
            (void*)&e1_W1, (void*)&e1_b1, (void*)&e1_W2, (void*)&e1_b2,
            (void*)&e2_W1, (void*)&e2_b1, (void*)&e2_W2, (void*)&e2_b2,
            (void*)&gWih, (void*)&gWhh, (void*)&gbih, (void*)&gbhh,
            (void*)&Wt, (void*)&h0b, (void*)&h1b, (void*)&rs, (void*)&ep,
            (void*)&Wpk4, (void*)&Wpk2, (void*)&outp
        };
        lerr = hipLaunchCooperativeKernel(fused_kernel, dim3(coop_grid), dim3(256),
                                          args, 0, stream);
        if (lerr != hipSuccess) { (void)hipGetLastError(); coop_grid = -1; }
    }

    if (lerr != hipSuccess) {
        // -------- fallback: previous 7-launch pipeline --------
        float*  h    = (float*)(ws + 221184);
        float*  agg  = (float*)(ws + 2141184);
        float*  sm   = (float*)(ws + 4061184);
        float4* fW4  = (float4*)(ws + 4121184);
        float2* fW2  = (float2*)(ws + 4137568);
        setup_kernel<<<(FB_TA + 255) / 256, 256, 0, stream>>>(
            node_ids, node_table, edge_table, proj_W, proj_b,
            e1_W1, e1_b1, e1_W2, e1_b2, e2_W1, e2_b1, e2_W2, e2_b2,
            gWih, gWhh, Wt, h, agg, fW4, fW2);
        for (int step = 0; step < 3; ++step) {
            edge_kernel<<<(N_EDGES * 32) / 256, 256, 0, stream>>>(
                srcp, dstp, edge_ids, h, Wt, attn_w, agg, sm);
            float* hout = (step == 2) ? outp : h;
            gru_kernel<<<(N_NODES * 32) / 256, 256, 0, stream>>>(
                agg, sm, h, fW4, fW2, gbih, gbhh, hout);
        }
    }
}